// Round 7
// baseline (144.342 us; speedup 1.0000x reference)
//
#include <hip/hip_runtime.h>
#include <cstdint>
#include <cstddef>

// T=1024 tokens, H=2048, F=1024, E=8, K=2
#define T_TOK 1024
#define H_DIM 2048
#define F_DIM 1024
#define E_EXP 8
#define BM 64
#define BK 64
#define SP 72          // B LDS row stride (144 B: b64 writes & b128 reads aligned)
#define MAX_TILES 40
#define ROWCAP 2560

// ---- workspace layout ----
#define I_NTILES 25     // int
#define I_TILE_E 32     // int[48]
#define I_TILE_R0 80    // int[48]
#define I_ROWTOK 4224   // int[2560]
#define I_ROWW   6784   // float[2560]
#define B_XB     37888                          // bf16 x [1024][2048]   (4 MB)
#define B_AWS    (B_XB + T_TOK*H_DIM*2)         // bf16 act [2560][1024] (5 MB)

typedef __bf16 bf16x8 __attribute__((ext_vector_type(8)));
typedef __bf16 bf16x4 __attribute__((ext_vector_type(4)));
typedef float  f32x4  __attribute__((ext_vector_type(4)));

#define MFMA(a,b,c) __builtin_amdgcn_mfma_f32_16x16x32_bf16(a,b,c,0,0,0)

__device__ __forceinline__ void gload16(const void* g, void* l) {
  __builtin_amdgcn_global_load_lds(
      (const __attribute__((address_space(1))) void*)g,
      (__attribute__((address_space(3))) void*)l, 16, 0, 0);
}

// ---------------- fused router + scan + assign ----------------
__global__ __launch_bounds__(1024) void k_route(const float* __restrict__ logits,
                                                int* __restrict__ ws_i) {
  __shared__ int cnt[E_EXP], cur[E_EXP], offs_s[E_EXP];
  const int t = threadIdx.x;
  float* ws_f = (float*)ws_i;
  if (t < E_EXP) { cnt[t] = 0; cur[t] = 0; }
  __syncthreads();
  float l[E_EXP];
#pragma unroll
  for (int e = 0; e < E_EXP; ++e) l[e] = logits[t * E_EXP + e];
  int b0 = 0; float v0 = l[0];
#pragma unroll
  for (int e = 1; e < E_EXP; ++e) if (l[e] > v0) { v0 = l[e]; b0 = e; }
  int b1 = -1; float v1 = -3.4e38f;
#pragma unroll
  for (int e = 0; e < E_EXP; ++e) if (e != b0 && l[e] > v1) { v1 = l[e]; b1 = e; }
  float w0 = 1.f / (1.f + __expf(v1 - v0));
  float w1 = 1.f - w0;
  atomicAdd(&cnt[b0], 1);
  atomicAdd(&cnt[b1], 1);
  __syncthreads();
  if (t == 0) {
    int off = 0, nt = 0;
    for (int e = 0; e < E_EXP; ++e) {
      offs_s[e] = off;
      int ntile = (cnt[e] + BM - 1) / BM;
      for (int i = 0; i < ntile; ++i) {
        ws_i[I_TILE_E + nt] = e;
        ws_i[I_TILE_R0 + nt] = off + i * BM;
        ++nt;
      }
      off += ntile * BM;
    }
    ws_i[I_NTILES] = nt;
  }
  for (int i = t; i < ROWCAP; i += 1024) ws_i[I_ROWTOK + i] = -1;
  __syncthreads();
  {
    int p = atomicAdd(&cur[b0], 1);
    int s = offs_s[b0] + p;
    ws_i[I_ROWTOK + s] = t;
    ws_f[I_ROWW + s] = w0;
  }
  {
    int p = atomicAdd(&cur[b1], 1);
    int s = offs_s[b1] + p;
    ws_i[I_ROWTOK + s] = t;
    ws_f[I_ROWW + s] = w1;
  }
}

// ---------------- x fp32 -> bf16 ----------------
__global__ __launch_bounds__(256) void k_cvt(const float* __restrict__ x,
                                             __bf16* __restrict__ xb) {
  long i = (long)(blockIdx.x * 256 + threadIdx.x) * 8;
  float4 a = *(const float4*)(x + i);
  float4 b = *(const float4*)(x + i + 4);
  bf16x8 v;
  v[0] = (__bf16)a.x; v[1] = (__bf16)a.y; v[2] = (__bf16)a.z; v[3] = (__bf16)a.w;
  v[4] = (__bf16)b.x; v[5] = (__bf16)b.y; v[6] = (__bf16)b.z; v[7] = (__bf16)b.w;
  *(bf16x8*)(xb + i) = v;
}

// ---------------- GEMM1: a = silu(x·w1)*(x·w3) -> aws bf16 ----------------
// A: bf16 xb via global_load_lds (pre-swizzled src, linear LDS, swizzled read).
// B: fp32 w1/w3 loaded 2 K-tiles ahead into reg sets, cvt+4x4-transpose, LDS [n][k].
// Double-buffered LDS, one barrier per K-step.
__global__ __launch_bounds__(256) void k_gemm1(const __bf16* __restrict__ xb,
                                               const float* __restrict__ w1,
                                               const float* __restrict__ w3,
                                               const int* __restrict__ ws_i,
                                               __bf16* __restrict__ aws) {
  __shared__ __bf16 Asm[2][4096];
  __shared__ __bf16 B1s[2][64][SP];
  __shared__ __bf16 B3s[2][64][SP];
  __shared__ int s_tok[BM];
  const int p = blockIdx.x;                   // 640 = 8 XCD * 80
  const int lg = (p & 7) * 80 + (p >> 3);
  const int tile = lg % MAX_TILES;
  const int n0 = (lg / MAX_TILES) * 64;
  if (tile >= ws_i[I_NTILES]) return;
  const int e  = ws_i[I_TILE_E + tile];
  const int r0 = ws_i[I_TILE_R0 + tile];
  const int tid = threadIdx.x, lane = tid & 63, wid = tid >> 6;
  const int wm = wid >> 1, wn = wid & 1;
  const int l15 = lane & 15, l4 = lane >> 4, lk8 = (lane >> 4) << 3;
  const int nb = (tid & 15) * 4, kq = (tid >> 4) * 4;   // B-staging 4x4 block
  if (tid < BM) {
    int tk = ws_i[I_ROWTOK + r0 + tid];
    s_tok[tid] = tk < 0 ? 0 : tk;     // padded rows compute garbage, never scattered
  }
  __syncthreads();
  // A staging geometry (r6-verbatim): lane covers row rj, source k-slot XOR-pre-swizzled
  const int rj0 = wid * 16 + (lane >> 3);
  const int rj1 = rj0 + 8;
  const int ks = ((lane & 7) ^ (lane >> 3)) * 8;
  const __bf16* gA0 = xb + (size_t)s_tok[rj0] * H_DIM + ks;
  const __bf16* gA1 = xb + (size_t)s_tok[rj1] * H_DIM + ks;
  const int c0 = wid * 2 * 512, c1 = c0 + 512;
  const float* pB1 = w1 + (size_t)e * H_DIM * F_DIM + n0 + nb;
  const float* pB3 = w3 + (size_t)e * H_DIM * F_DIM + n0 + nb;

  f32x4 qa1[4], qa3[4], qb1[4], qb3[4];   // two named staging sets (rule #20)

  auto STAGEA = [&](int b, int t) {
    gload16(gA0 + t * BK, &Asm[b][c0]);
    gload16(gA1 + t * BK, &Asm[b][c1]);
  };
  auto LOADR = [&](f32x4 (&q1)[4], f32x4 (&q3)[4], int t) {
    const int k0 = t * BK + kq;
#pragma unroll
    for (int j = 0; j < 4; ++j) {
      q1[j] = *(const f32x4*)(pB1 + (size_t)(k0 + j) * F_DIM);
      q3[j] = *(const f32x4*)(pB3 + (size_t)(k0 + j) * F_DIM);
    }
  };
  auto WRITEB = [&](int b, f32x4 (&q1)[4], f32x4 (&q3)[4]) {
#pragma unroll
    for (int u = 0; u < 4; ++u) {
      bf16x4 v1, v3;
#pragma unroll
      for (int j = 0; j < 4; ++j) { v1[j] = (__bf16)q1[j][u]; v3[j] = (__bf16)q3[j][u]; }
      *(bf16x4*)&B1s[b][nb + u][kq] = v1;
      *(bf16x4*)&B3s[b][nb + u][kq] = v3;
    }
  };

  f32x4 accg[2][2] = {}; f32x4 accu[2][2] = {};
  auto COMPUTE = [&](int b) {
    const __bf16* As = &Asm[b][0];
    __builtin_amdgcn_s_setprio(1);
#pragma unroll
    for (int kk = 0; kk < 2; ++kk) {
      const int sx = ((kk * 4 + l4) ^ (lane & 7)) << 3;
      const int kb = kk * 32 + lk8;
      bf16x8 a0  = *(const bf16x8*)&As[(wm * 32 + l15) * 64 + sx];
      bf16x8 a1  = *(const bf16x8*)&As[(wm * 32 + 16 + l15) * 64 + sx];
      bf16x8 b10 = *(const bf16x8*)&B1s[b][wn * 32 + l15][kb];
      bf16x8 b11 = *(const bf16x8*)&B1s[b][wn * 32 + 16 + l15][kb];
      bf16x8 b30 = *(const bf16x8*)&B3s[b][wn * 32 + l15][kb];
      bf16x8 b31 = *(const bf16x8*)&B3s[b][wn * 32 + 16 + l15][kb];
      accg[0][0] = MFMA(a0, b10, accg[0][0]);
      accg[0][1] = MFMA(a0, b11, accg[0][1]);
      accg[1][0] = MFMA(a1, b10, accg[1][0]);
      accg[1][1] = MFMA(a1, b11, accg[1][1]);
      accu[0][0] = MFMA(a0, b30, accu[0][0]);
      accu[0][1] = MFMA(a0, b31, accu[0][1]);
      accu[1][0] = MFMA(a1, b30, accu[1][0]);
      accu[1][1] = MFMA(a1, b31, accu[1][1]);
    }
    __builtin_amdgcn_s_setprio(0);
  };

  const int NT = H_DIM / BK;   // 32 (even)
  // prologue: sets qa<-tile0, qb<-tile1; write tile0; reload qa<-tile2
  LOADR(qa1, qa3, 0);
  LOADR(qb1, qb3, 1);
  STAGEA(0, 0);
  WRITEB(0, qa1, qa3);
  LOADR(qa1, qa3, 2);
  __syncthreads();
  for (int t = 0; t < NT; t += 2) {
    // iter t: compute buf0(tile t); stage tile t+1 into buf1 (qb), reload qb<-t+3
    if (t + 1 < NT) { STAGEA(1, t + 1); WRITEB(1, qb1, qb3); }
    if (t + 3 < NT) LOADR(qb1, qb3, t + 3);
    COMPUTE(0);
    __syncthreads();
    // iter t+1: compute buf1(tile t+1); stage tile t+2 into buf0 (qa), reload qa<-t+4
    if (t + 2 < NT) { STAGEA(0, t + 2); WRITEB(0, qa1, qa3); }
    if (t + 4 < NT) LOADR(qa1, qa3, t + 4);
    COMPUTE(1);
    __syncthreads();
  }
  // epilogue: silu(g)*u -> bf16 (C layout: col=lane&15, row=(lane>>4)*4+reg)
#pragma unroll
  for (int fm = 0; fm < 2; ++fm)
#pragma unroll
    for (int fn = 0; fn < 2; ++fn)
#pragma unroll
      for (int r = 0; r < 4; ++r) {
        float g = accg[fm][fn][r], u = accu[fm][fn][r];
        float a = g / (1.f + __expf(-g)) * u;
        int row = r0 + wm * 32 + fm * 16 + l4 * 4 + r;
        int col = n0 + wn * 32 + fn * 16 + l15;
        aws[(size_t)row * F_DIM + col] = (__bf16)a;
      }
}

// ---------------- GEMM2: y = a·w2, weighted atomic scatter ----------------
__global__ __launch_bounds__(256) void k_gemm2(const __bf16* __restrict__ aws,
                                               const float* __restrict__ w2,
                                               const int* __restrict__ ws_i,
                                               float* __restrict__ out) {
  __shared__ __bf16 Asm[2][4096];
  __shared__ __bf16 Bs[2][64][SP];
  __shared__ int s_tok[BM];
  __shared__ float s_w[BM];
  const int p = blockIdx.x;                 // 1280 = 8 XCD * 160
  const int lg = (p & 7) * 160 + (p >> 3);
  const int tile = lg % MAX_TILES;
  const int h0 = (lg / MAX_TILES) * 64;
  if (tile >= ws_i[I_NTILES]) return;
  const int e  = ws_i[I_TILE_E + tile];
  const int r0 = ws_i[I_TILE_R0 + tile];
  const int tid = threadIdx.x, lane = tid & 63, wid = tid >> 6;
  const int wm = wid >> 1, wn = wid & 1;
  const int l15 = lane & 15, l4 = lane >> 4, lk8 = (lane >> 4) << 3;
  const int nb = (tid & 15) * 4, kq = (tid >> 4) * 4;
  const float* ws_f = (const float*)ws_i;
  if (tid < BM) {
    s_tok[tid] = ws_i[I_ROWTOK + r0 + tid];
    s_w[tid]   = ws_f[I_ROWW + r0 + tid];
  }
  __syncthreads();
  const int rj0 = wid * 16 + (lane >> 3);
  const int rj1 = rj0 + 8;
  const int ks = ((lane & 7) ^ (lane >> 3)) * 8;
  const __bf16* gA0 = aws + (size_t)(r0 + rj0) * F_DIM + ks;
  const __bf16* gA1 = aws + (size_t)(r0 + rj1) * F_DIM + ks;
  const int c0 = wid * 2 * 512, c1 = c0 + 512;
  const float* pB2 = w2 + (size_t)e * F_DIM * H_DIM + h0 + nb;

  f32x4 qa2[4], qb2[4];

  auto STAGEA = [&](int b, int t) {
    gload16(gA0 + t * BK, &Asm[b][c0]);
    gload16(gA1 + t * BK, &Asm[b][c1]);
  };
  auto LOADR = [&](f32x4 (&q2)[4], int t) {
    const int k0 = t * BK + kq;
#pragma unroll
    for (int j = 0; j < 4; ++j)
      q2[j] = *(const f32x4*)(pB2 + (size_t)(k0 + j) * H_DIM);
  };
  auto WRITEB = [&](int b, f32x4 (&q2)[4]) {
#pragma unroll
    for (int u = 0; u < 4; ++u) {
      bf16x4 v;
#pragma unroll
      for (int j = 0; j < 4; ++j) v[j] = (__bf16)q2[j][u];
      *(bf16x4*)&Bs[b][nb + u][kq] = v;
    }
  };

  f32x4 acc[2][2] = {};
  auto COMPUTE = [&](int b) {
    const __bf16* As = &Asm[b][0];
    __builtin_amdgcn_s_setprio(1);
#pragma unroll
    for (int kk = 0; kk < 2; ++kk) {
      const int sx = ((kk * 4 + l4) ^ (lane & 7)) << 3;
      const int kb = kk * 32 + lk8;
      bf16x8 a0 = *(const bf16x8*)&As[(wm * 32 + l15) * 64 + sx];
      bf16x8 a1 = *(const bf16x8*)&As[(wm * 32 + 16 + l15) * 64 + sx];
      bf16x8 b0 = *(const bf16x8*)&Bs[b][wn * 32 + l15][kb];
      bf16x8 b1 = *(const bf16x8*)&Bs[b][wn * 32 + 16 + l15][kb];
      acc[0][0] = MFMA(a0, b0, acc[0][0]);
      acc[0][1] = MFMA(a0, b1, acc[0][1]);
      acc[1][0] = MFMA(a1, b0, acc[1][0]);
      acc[1][1] = MFMA(a1, b1, acc[1][1]);
    }
    __builtin_amdgcn_s_setprio(0);
  };

  const int NT = F_DIM / BK;   // 16 (even)
  LOADR(qa2, 0);
  LOADR(qb2, 1);
  STAGEA(0, 0);
  WRITEB(0, qa2);
  LOADR(qa2, 2);
  __syncthreads();
  for (int t = 0; t < NT; t += 2) {
    if (t + 1 < NT) { STAGEA(1, t + 1); WRITEB(1, qb2); }
    if (t + 3 < NT) LOADR(qb2, t + 3);
    COMPUTE(0);
    __syncthreads();
    if (t + 2 < NT) { STAGEA(0, t + 2); WRITEB(0, qa2); }
    if (t + 4 < NT) LOADR(qa2, t + 4);
    COMPUTE(1);
    __syncthreads();
  }
  // exactly 2 atomic adds per output element (K=2): order-independent (a+b exact)
#pragma unroll
  for (int fm = 0; fm < 2; ++fm)
#pragma unroll
    for (int fn = 0; fn < 2; ++fn)
#pragma unroll
      for (int r = 0; r < 4; ++r) {
        int lrow = wm * 32 + fm * 16 + l4 * 4 + r;
        int t = s_tok[lrow];
        if (t >= 0) {
          float v = acc[fm][fn][r] * s_w[lrow];
          atomicAdd(out + (size_t)t * H_DIM + h0 + wn * 32 + fn * 16 + l15, v);
        }
      }
}

extern "C" void kernel_launch(void* const* d_in, const int* in_sizes, int n_in,
                              void* d_out, int out_size, void* d_ws, size_t ws_size,
                              hipStream_t stream) {
  (void)in_sizes; (void)n_in; (void)out_size; (void)ws_size;
  const float* x      = (const float*)d_in[0];
  const float* logits = (const float*)d_in[1];
  const float* w1     = (const float*)d_in[2];
  const float* w3     = (const float*)d_in[3];
  const float* w2     = (const float*)d_in[4];
  float* out = (float*)d_out;
  int* ws_i = (int*)d_ws;
  __bf16* xb  = (__bf16*)((char*)d_ws + B_XB);
  __bf16* aws = (__bf16*)((char*)d_ws + B_AWS);

  hipMemsetAsync(d_out, 0, (size_t)T_TOK * H_DIM * sizeof(float), stream);
  k_route<<<1, 1024, 0, stream>>>(logits, ws_i);
  k_cvt<<<dim3(T_TOK * H_DIM / (256 * 8)), 256, 0, stream>>>(x, xb);
  k_gemm1<<<dim3(MAX_TILES * (F_DIM / 64)), 256, 0, stream>>>(xb, w1, w3, ws_i, aws);
  k_gemm2<<<dim3(MAX_TILES * (H_DIM / 64)), 256, 0, stream>>>(aws, w2, ws_i, out);
}